// Round 17
// baseline (181.987 us; speedup 1.0000x reference)
//
#include <hip/hip_runtime.h>
#include <math.h>

#define BS   2
#define PP   1024
#define NN   16
#define CIN  64
#define DOUT 32
#define KK   7
#define NR   60
#define NT2  30         // tiles of 2 rotations (one rr-pair per block)

// ws layout (units: 4-byte elements)
#define OFF_NDN  0              // BS*PP*NN*3        = 98304   [b][p][n][3]
#define OFF_KROT 98304          // DOUT*NR*KK*3      = 40320
#define OFF_M    138624         // BS*DOUT*PP*64     = 4194304
#define OFF_PVAL 4332928        // BS*DOUT*NT2*PP    = 1966080
#define OFF_PIDX 6299008        // BS*DOUT*NT2*PP bytes = 491520 elems
#define OFF_FO2  6790528        // BS*DOUT*PP*8      = 524288
#define OFF_RIDX 7314816        // BS*DOUT*PP        = 65536 (int)
#define OFF_CEN  7380352        // BS*DOUT*PP*3      = 196608
// total = 7576960 elements = 30.3 MB

#define NEG_INF (-3.402823466e38f)

typedef float v2f __attribute__((ext_vector_type(2)));
typedef float v4f __attribute__((ext_vector_type(4)));

__device__ __forceinline__ float sload(const float* __restrict__ p, int idx) {
    // force wave-uniform value into an SGPR
    return __int_as_float(__builtin_amdgcn_readfirstlane(__float_as_int(p[idx])));
}

// packed fp32 ops (VOP3P) — 2 lanes of math per instruction
__device__ __forceinline__ v2f pk_mul_sv(v2f s, v2f v) {
    v2f d; asm("v_pk_mul_f32 %0, %1, %2" : "=v"(d) : "s"(s), "v"(v)); return d;
}
__device__ __forceinline__ v2f pk_fma_svv(v2f s, v2f v, v2f c) {
    v2f d; asm("v_pk_fma_f32 %0, %1, %2, %3" : "=v"(d) : "s"(s), "v"(v), "v"(c)); return d;
}
__device__ __forceinline__ v2f pk_mul_vv(v2f a, v2f b) {
    v2f d; asm("v_pk_mul_f32 %0, %1, %2" : "=v"(d) : "v"(a), "v"(b)); return d;
}

// quad max via DPP quad_perm (VALU pipe only)
__device__ __forceinline__ float quad_max(float x) {
    float y = __int_as_float(__builtin_amdgcn_mov_dpp(
        __float_as_int(x), 0xB1, 0xF, 0xF, true));   // [1,0,3,2] : xor 1
    x = fmaxf(x, y);
    float z = __int_as_float(__builtin_amdgcn_mov_dpp(
        __float_as_int(x), 0x4E, 0xF, 0xF, true));   // [2,3,0,1] : xor 2
    return fmaxf(x, z);
}

// ---------------------------------------------------------------------------
// k_prebuild: fused k_pre + k_buildM (data-independent -> one dispatch).
// Blocks [0,256): buildM  (b,d,px decoded from blockIdx.x)
// Blocks [256,437): pre   (ndn normalize + krot table)
// ---------------------------------------------------------------------------
__global__ __launch_bounds__(256, 2) void k_prebuild(
        const int* __restrict__ nbr,
        const float* __restrict__ vert,
        const float* __restrict__ dirs,
        const float* __restrict__ Rs,
        const float* __restrict__ fm,
        const float* __restrict__ W,
        const float* __restrict__ Wc,
        float* __restrict__ ws) {
    int id = blockIdx.x;
    if (id < 256) {
        // ---- buildM + center ----
        int px = id & 3, d = (id >> 2) & 31, b = id >> 7;
        int p = px * 256 + threadIdx.x;

        float M[64];
#pragma unroll
        for (int t = 0; t < 64; t++) M[t] = 0.f;
        float c0 = 0.f, c1 = 0.f, c2 = 0.f;

        const float* fbase = fm + (size_t)(b * CIN * PP + p) * 3;
        const float* wbase = W + (size_t)d * CIN * KK * 3;
        const float* wrow = Wc + d * CIN;
        for (int c = 0; c < CIN; c++) {
            const float* f = fbase + c * PP * 3;
            float f0 = f[0], f1 = f[1], f2 = f[2];
            const float* wl = wbase + c * 21;
#pragma unroll
            for (int k = 0; k < KK; k++) {
#pragma unroll
                for (int j = 0; j < 3; j++) {
                    float w = sload(wl, k * 3 + j);
                    M[k * 9 + 0 + j] += w * f0;
                    M[k * 9 + 3 + j] += w * f1;
                    M[k * 9 + 6 + j] += w * f2;
                }
            }
            float wcv = sload(wrow, c);
            c0 += wcv * f0; c1 += wcv * f1; c2 += wcv * f2;
        }
        int gid = ((b * DOUT + d) << 10) + p;
        float4* o = (float4*)(ws + OFF_M + (size_t)gid * 64);
#pragma unroll
        for (int t = 0; t < 15; t++)
            o[t] = make_float4(M[4 * t], M[4 * t + 1], M[4 * t + 2], M[4 * t + 3]);
        o[15] = make_float4(M[60], M[61], M[62], 0.f);
        float* cp = ws + OFF_CEN + (size_t)gid * 3;
        cp[0] = c0; cp[1] = c1; cp[2] = c2;
    } else {
        // ---- pre: ndn + krot ----
        int tid = (id - 256) * 256 + threadIdx.x;
        if (tid < BS * PP * NN) {
            int p = (tid >> 4) & (PP - 1);
            int b = tid >> 14;
            int q = nbr[tid];
            const float* vp = vert + ((b << 10) + p) * 3;
            const float* vq = vert + ((b << 10) + q) * 3;
            float dx = vq[0] - vp[0], dy = vq[1] - vp[1], dz = vq[2] - vp[2];
            float nrm = sqrtf(dx * dx + dy * dy + dz * dz);
            float den = fmaxf(nrm, 1e-12f);
            dx /= den; dy /= den; dz /= den;
            float* o = ws + OFF_NDN + tid * 3;
            o[0] = dx; o[1] = dy; o[2] = dz;
        }
        int t2 = tid - BS * PP * NN;
        if (t2 >= 0 && t2 < DOUT * NR * KK) {
            int k = t2 % KK;
            int r = (t2 / KK) % NR;
            int d = t2 / (KK * NR);
            const float* dk = dirs + (d * KK + k) * 3;
            float x = dk[0], y = dk[1], z = dk[2];
            float nrm = sqrtf(x * x + y * y + z * z);
            float den = fmaxf(nrm, 1e-12f);
            x /= den; y /= den; z /= den;
            const float* R = Rs + r * 9;
            float* o = ws + OFF_KROT + t2 * 3;   // t2 == (d*NR+r)*KK+k
            o[0] = R[0] * x + R[1] * y + R[2] * z;
            o[1] = R[3] * x + R[4] * y + R[5] * z;
            o[2] = R[6] * x + R[7] * y + R[8] * z;
        }
    }
}

// ---------------------------------------------------------------------------
// interleaved-row swizzle (k_score): row p -> float4 slots (p<<2|j)^((p>>1)&7)
// ---------------------------------------------------------------------------
__device__ __forceinline__ int fo_base(int p) {
    return (p << 2) ^ ((p >> 1) & 7);
}

// ---------------------------------------------------------------------------
// k_score: ONE rotation-pair per block (grid 30x32x2 = 1920 blocks).
// Round-14 structure (convoy broken by per-n sched_barrier, packed fp32 pair
// math, 64 KiB LDS / 2 blocks/CU) + PREFETCH DISTANCE 2: gathers for n+2
// issued in region n, doubling DS-latency cover (~200 cyc) per wait.
// ---------------------------------------------------------------------------
__global__ __launch_bounds__(1024)
void k_score(const int* __restrict__ nbr,
             const float* __restrict__ Rs,
             const float* __restrict__ Mptr,
             const float* __restrict__ ndn,
             const float* __restrict__ krot,
             float* __restrict__ pval,
             unsigned char* __restrict__ pidx8) {
    __shared__ v4f fo4s[PP * 4];          // 64 KiB exactly
    const int tile = blockIdx.x, d = blockIdx.y, b = blockIdx.z;
    const int bd = b * DOUT + d;
    const int rbase = tile * 2;
    const int tq = threadIdx.x >> 2;      // point-group
    const int ns = threadIdx.x & 3;       // neighbor subset

    // ---- Phase A ----
    {
        const int p = threadIdx.x;
        float Rc0[9], Rc1[9];
#pragma unroll
        for (int j = 0; j < 9; j++) {
            Rc0[j] = sload(Rs, (rbase + 0) * 9 + j);
            Rc1[j] = sload(Rs, (rbase + 1) * 9 + j);
        }
        float fo0[KK], fo1[KK];
#pragma unroll
        for (int k = 0; k < KK; k++) { fo0[k] = 0.f; fo1[k] = 0.f; }

        const float4* m4 = (const float4*)(Mptr + (size_t)((bd << 10) + p) * 64);
#pragma unroll
        for (int t = 0; t < 16; t++) {           // t compile-time
            float4 v = m4[t];
            float e[4] = {v.x, v.y, v.z, v.w};
#pragma unroll
            for (int ee = 0; ee < 4; ee++) {
                const int g = 4 * t + ee;        // compile-time
                if (g < 63) {
                    const int k = g / 9, r9 = g % 9;
                    fo0[k] += Rc0[r9] * e[ee];
                    fo1[k] += Rc1[r9] * e[ee];
                }
            }
            if ((t & 3) == 3)
                __builtin_amdgcn_sched_barrier(0);   // cap in-flight loads
        }
        const int fb = fo_base(p);
        v4f s0; s0.x = fo0[0]; s0.y = fo1[0]; s0.z = fo0[1]; s0.w = fo1[1];
        v4f s1; s1.x = fo0[2]; s1.y = fo1[2]; s1.z = fo0[3]; s1.w = fo1[3];
        v4f s2; s2.x = fo0[4]; s2.y = fo1[4]; s2.z = fo0[5]; s2.w = fo1[5];
        v4f s3; s3.x = fo0[6]; s3.y = fo1[6]; s3.z = 0.f;    s3.w = 0.f;
        fo4s[fb]     = s0;
        fo4s[fb ^ 1] = s1;
        fo4s[fb ^ 2] = s2;
        fo4s[fb ^ 3] = s3;
    }
    __syncthreads();

    // ---- Phase B ----
    v2f vkp[KK][3];   // krot pairs [rr0, rr1] -> SGPR pairs
    {
        const int kb0 = (d * NR + rbase + 0) * 21;
        const int kb1 = (d * NR + rbase + 1) * 21;
#pragma unroll
        for (int k = 0; k < KK; k++)
#pragma unroll
            for (int c = 0; c < 3; c++) {
                v2f t; t.x = sload(krot, kb0 + k * 3 + c);
                       t.y = sload(krot, kb1 + k * 3 + c);
                vkp[k][c] = t;
            }
    }
    const v2f* fo2s = (const v2f*)fo4s;

#pragma unroll
    for (int pp = 0; pp < 4; pp++) {
        const int p2 = (pp << 8) + tq;

        int4 nv = *(const int4*)(nbr + (((size_t)((b << 10) + p2)) << 4) + (ns << 2));
        float u[12];
        {
            const float4* u4 = (const float4*)(ndn + ((size_t)((b << 10) + p2) * 16 + (ns << 2)) * 3);
            float4 a = u4[0], bb = u4[1], cc = u4[2];
            u[0] = a.x;  u[1] = a.y;  u[2] = a.z;  u[3] = a.w;
            u[4] = bb.x; u[5] = bb.y; u[6] = bb.z; u[7] = bb.w;
            u[8] = cc.x; u[9] = cc.y; u[10] = cc.z; u[11] = cc.w;
        }

        float mk0[KK], mk1[KK];
#pragma unroll
        for (int k = 0; k < KK; k++) { mk0[k] = NEG_INF; mk1[k] = NEG_INF; }

        // prefetch n=0 and n=1 gathers (distance-2 pipeline)
        v4f Aa, Ba, Ca; v2f Da;   // current (n)
        v4f Ab, Bb, Cb; v2f Db;   // next (n+1)
        {
            int c0 = fo_base(nv.x);
            Aa = fo4s[c0]; Ba = fo4s[c0 ^ 1]; Ca = fo4s[c0 ^ 2];
            Da = fo2s[(c0 ^ 3) << 1];
            int c1 = fo_base(nv.y);
            Ab = fo4s[c1]; Bb = fo4s[c1 ^ 1]; Cb = fo4s[c1 ^ 2];
            Db = fo2s[(c1 ^ 3) << 1];
        }

#pragma unroll
        for (int n = 0; n < 4; n++) {     // n compile-time
            // issue n+2's gathers before consuming n
            v4f Ac, Bc, Cc; v2f Dc;
            if (n < 2) {
                int qn = (n == 0) ? nv.z : nv.w;
                int cn = fo_base(qn);
                Ac = fo4s[cn]; Bc = fo4s[cn ^ 1]; Cc = fo4s[cn ^ 2];
                Dc = fo2s[(cn ^ 3) << 1];
            }
            float u0 = u[n * 3], u1 = u[n * 3 + 1], u2 = u[n * 3 + 2];
            v2f u00; u00.x = u0; u00.y = u0;
            v2f u11; u11.x = u1; u11.y = u1;
            v2f u22; u22.x = u2; u22.y = u2;
#pragma unroll
            for (int k = 0; k < KK; k++) {
                v2f g;
                if (k == 0)      g = __builtin_shufflevector(Aa, Aa, 0, 1);
                else if (k == 1) g = __builtin_shufflevector(Aa, Aa, 2, 3);
                else if (k == 2) g = __builtin_shufflevector(Ba, Ba, 0, 1);
                else if (k == 3) g = __builtin_shufflevector(Ba, Ba, 2, 3);
                else if (k == 4) g = __builtin_shufflevector(Ca, Ca, 0, 1);
                else if (k == 5) g = __builtin_shufflevector(Ca, Ca, 2, 3);
                else             g = Da;
                v2f t = pk_mul_sv(vkp[k][0], u00);
                t = pk_fma_svv(vkp[k][1], u11, t);
                t = pk_fma_svv(vkp[k][2], u22, t);
                v2f pr = pk_mul_vv(g, t);
                mk0[k] = fmaxf(mk0[k], pr.x);
                mk1[k] = fmaxf(mk1[k], pr.y);
            }
            // rotate the pipeline registers
            Aa = Ab; Ba = Bb; Ca = Cb; Da = Db;
            if (n < 2) { Ab = Ac; Bb = Bc; Cb = Cc; Db = Dc; }
            // break the DS-burst convoy: pin each n's [DS][VALU] region
            __builtin_amdgcn_sched_barrier(0);
        }
        // finish max over 16 neighbors: DPP quad butterfly
#pragma unroll
        for (int k = 0; k < KK; k++) {
            mk0[k] = quad_max(mk0[k]);
            mk1[k] = quad_max(mk1[k]);
        }
        float s0 = ((mk0[0] + mk0[1]) + (mk0[2] + mk0[3])) + ((mk0[4] + mk0[5]) + mk0[6]);
        float s1 = ((mk1[0] + mk1[1]) + (mk1[2] + mk1[3])) + ((mk1[4] + mk1[5]) + mk1[6]);
        float bl = s0; int bil = rbase;
        if (s1 > bl) { bl = s1; bil = rbase + 1; }

        if (ns == 0) {
            int pi = (bd * NT2 + tile) * PP + p2;
            pval[pi] = bl;
            pidx8[pi] = (unsigned char)bil;
        }
    }
}

// ---------------------------------------------------------------------------
// k_reduce: final argmax over 30 pair-partials; fo2[k] = <R_ri, M[p]>
// ---------------------------------------------------------------------------
__global__ __launch_bounds__(256, 2) void k_reduce(const float* __restrict__ Rs,
                                                   float* __restrict__ ws) {
    int gid = blockIdx.x * 256 + threadIdx.x;   // (b*DOUT+d)*PP + p
    int bd = gid >> 10;
    int p = gid & (PP - 1);
    const unsigned char* pidx8 = (const unsigned char*)(ws + OFF_PIDX);
    float best = NEG_INF;
    int bi = 0;
    for (int t = 0; t < NT2; t++) {
        float v = ws[OFF_PVAL + (bd * NT2 + t) * PP + p];
        int idx = pidx8[(bd * NT2 + t) * PP + p];
        if (v > best) { best = v; bi = idx; }
    }
    ((int*)ws)[OFF_RIDX + gid] = bi;

    const float* R = Rs + bi * 9;
    float R0 = R[0], R1 = R[1], R2 = R[2];
    float R3 = R[3], R4 = R[4], R5 = R[5];
    float R6 = R[6], R7 = R[7], R8 = R[8];

    float M[64];
    const float4* m4 = (const float4*)(ws + OFF_M + (size_t)gid * 64);
#pragma unroll
    for (int t = 0; t < 16; t++) {
        float4 v = m4[t];
        M[4 * t] = v.x; M[4 * t + 1] = v.y; M[4 * t + 2] = v.z; M[4 * t + 3] = v.w;
    }
    float* o = ws + OFF_FO2 + (size_t)gid * 8;
#pragma unroll
    for (int k = 0; k < KK; k++) {
        o[k] = R0 * M[k * 9 + 0] + R1 * M[k * 9 + 1] + R2 * M[k * 9 + 2]
             + R3 * M[k * 9 + 3] + R4 * M[k * 9 + 4] + R5 * M[k * 9 + 5]
             + R6 * M[k * 9 + 6] + R7 * M[k * 9 + 7] + R8 * M[k * 9 + 8];
    }
    o[7] = 0.f;
}

// ---------------------------------------------------------------------------
// k_final: theta2 = relu(<krot[ri,k], ndn>), gather neighbor fo2 from LDS,
// kaw = max_n, out = sum_k kaw*krot + cen (precomputed in k_prebuild)
// ---------------------------------------------------------------------------
__global__ __launch_bounds__(256, 2) void k_final(const int* __restrict__ nbr,
                                                  const float* __restrict__ ws,
                                                  float* __restrict__ out) {
    __shared__ float fo2_s[PP * 8];        // 32 KiB
    __shared__ float krot_s[NR * KK * 3];  // 5040 B
    int d = blockIdx.y, b = blockIdx.z;
    int bd = b * DOUT + d;
    for (int i = threadIdx.x; i < PP * 8; i += 256)
        fo2_s[i] = ws[OFF_FO2 + (size_t)bd * PP * 8 + i];
    for (int i = threadIdx.x; i < NR * KK * 3; i += 256)
        krot_s[i] = ws[OFF_KROT + d * NR * KK * 3 + i];
    __syncthreads();

    int p = blockIdx.x * 256 + threadIdx.x;
    int gid = (bd << 10) + p;
    int ri = ((const int*)ws)[OFF_RIDX + gid];

    float v[21];
#pragma unroll
    for (int t = 0; t < 21; t++) v[t] = krot_s[ri * 21 + t];

    float u[48];
    {
        const float4* u4 = (const float4*)(ws + OFF_NDN + (size_t)((b << 10) + p) * 48);
#pragma unroll
        for (int t = 0; t < 12; t++) {
            float4 w = u4[t];
            u[4 * t] = w.x; u[4 * t + 1] = w.y; u[4 * t + 2] = w.z; u[4 * t + 3] = w.w;
        }
    }
    int nidx[16];
    {
        const int4* n4 = (const int4*)(nbr + (size_t)((b << 10) + p) * 16);
#pragma unroll
        for (int t = 0; t < 4; t++) {
            int4 w = n4[t];
            nidx[4 * t] = w.x; nidx[4 * t + 1] = w.y; nidx[4 * t + 2] = w.z; nidx[4 * t + 3] = w.w;
        }
    }

    float kaw[7];
#pragma unroll
    for (int k = 0; k < KK; k++) kaw[k] = NEG_INF;
#pragma unroll
    for (int n = 0; n < NN; n++) {
        int q = nidx[n];
        const float4* fq = (const float4*)&fo2_s[q * 8];
        float4 a = fq[0], c4 = fq[1];
        float g[7] = {a.x, a.y, a.z, a.w, c4.x, c4.y, c4.z};
        float u0 = u[n * 3], u1 = u[n * 3 + 1], u2 = u[n * 3 + 2];
#pragma unroll
        for (int k = 0; k < KK; k++) {
            float th = fmaxf(v[k * 3] * u0 + v[k * 3 + 1] * u1 + v[k * 3 + 2] * u2, 0.f);
            kaw[k] = fmaxf(kaw[k], g[k] * th);
        }
    }
    float o0 = 0.f, o1 = 0.f, o2 = 0.f;
#pragma unroll
    for (int k = 0; k < KK; k++) {
        o0 += kaw[k] * v[k * 3];
        o1 += kaw[k] * v[k * 3 + 1];
        o2 += kaw[k] * v[k * 3 + 2];
    }
    const float* cp = ws + OFF_CEN + (size_t)gid * 3;
    out[(size_t)gid * 3 + 0] = o0 + cp[0];
    out[(size_t)gid * 3 + 1] = o1 + cp[1];
    out[(size_t)gid * 3 + 2] = o2 + cp[2];
}

// ---------------------------------------------------------------------------
extern "C" void kernel_launch(void* const* d_in, const int* in_sizes, int n_in,
                              void* d_out, int out_size, void* d_ws, size_t ws_size,
                              hipStream_t stream) {
    const int*   nbr  = (const int*)d_in[0];
    const float* vert = (const float*)d_in[1];
    const float* fm   = (const float*)d_in[2];
    const float* W    = (const float*)d_in[3];
    const float* Wc   = (const float*)d_in[4];
    const float* dirs = (const float*)d_in[5];
    const float* Rs   = (const float*)d_in[6];
    float* ws  = (float*)d_ws;
    float* out = (float*)d_out;

    k_prebuild<<<437, 256, 0, stream>>>(nbr, vert, dirs, Rs, fm, W, Wc, ws);
    k_score<<<dim3(NT2, DOUT, BS), 1024, 0, stream>>>(
        nbr, Rs, ws + OFF_M, ws + OFF_NDN, ws + OFF_KROT,
        ws + OFF_PVAL, (unsigned char*)(ws + OFF_PIDX));
    k_reduce<<<dim3(BS * DOUT * PP / 256), 256, 0, stream>>>(Rs, ws);
    k_final<<<dim3(PP / 256, DOUT, BS), 256, 0, stream>>>(nbr, ws, out);
}

// Round 18
// 156.448 us; speedup vs baseline: 1.1632x; 1.1632x over previous
//
#include <hip/hip_runtime.h>
#include <math.h>

#define BS   2
#define PP   1024
#define NN   16
#define CIN  64
#define DOUT 32
#define KK   7
#define NR   60
#define NT2  30         // tiles of 2 rotations (one rr-pair per block)

// ws layout (units: 4-byte elements)
#define OFF_NDN  0              // BS*PP*NN*3        = 98304   [b][p][n][3]
#define OFF_KROT 98304          // DOUT*NR*KK*3      = 40320
#define OFF_M    138624         // BS*DOUT*PP*64     = 4194304
#define OFF_PVAL 4332928        // BS*DOUT*NT2*PP    = 1966080
#define OFF_PIDX 6299008        // BS*DOUT*NT2*PP bytes = 491520 elems
#define OFF_FO2  6790528        // BS*DOUT*PP*8      = 524288
#define OFF_RIDX 7314816        // BS*DOUT*PP        = 65536 (int)
#define OFF_CEN  7380352        // BS*DOUT*PP*3      = 196608
// total = 7576960 elements = 30.3 MB

#define NEG_INF (-3.402823466e38f)

typedef float v2f __attribute__((ext_vector_type(2)));
typedef float v4f __attribute__((ext_vector_type(4)));

__device__ __forceinline__ float sload(const float* __restrict__ p, int idx) {
    // force wave-uniform value into an SGPR
    return __int_as_float(__builtin_amdgcn_readfirstlane(__float_as_int(p[idx])));
}

// packed fp32 ops (VOP3P) — 2 lanes of math per instruction
__device__ __forceinline__ v2f pk_mul_sv(v2f s, v2f v) {
    v2f d; asm("v_pk_mul_f32 %0, %1, %2" : "=v"(d) : "s"(s), "v"(v)); return d;
}
__device__ __forceinline__ v2f pk_fma_svv(v2f s, v2f v, v2f c) {
    v2f d; asm("v_pk_fma_f32 %0, %1, %2, %3" : "=v"(d) : "s"(s), "v"(v), "v"(c)); return d;
}
__device__ __forceinline__ v2f pk_mul_vv(v2f a, v2f b) {
    v2f d; asm("v_pk_mul_f32 %0, %1, %2" : "=v"(d) : "v"(a), "v"(b)); return d;
}

// quad max via DPP quad_perm (VALU pipe only)
__device__ __forceinline__ float quad_max(float x) {
    float y = __int_as_float(__builtin_amdgcn_mov_dpp(
        __float_as_int(x), 0xB1, 0xF, 0xF, true));   // [1,0,3,2] : xor 1
    x = fmaxf(x, y);
    float z = __int_as_float(__builtin_amdgcn_mov_dpp(
        __float_as_int(x), 0x4E, 0xF, 0xF, true));   // [2,3,0,1] : xor 2
    return fmaxf(x, z);
}

// ---------------------------------------------------------------------------
// k_prebuild: fused k_pre + k_buildM (data-independent -> one dispatch).
// Blocks [0,256): buildM  (b,d,px decoded from blockIdx.x)
// Blocks [256,437): pre   (ndn normalize + krot table)
// ---------------------------------------------------------------------------
__global__ __launch_bounds__(256, 2) void k_prebuild(
        const int* __restrict__ nbr,
        const float* __restrict__ vert,
        const float* __restrict__ dirs,
        const float* __restrict__ Rs,
        const float* __restrict__ fm,
        const float* __restrict__ W,
        const float* __restrict__ Wc,
        float* __restrict__ ws) {
    int id = blockIdx.x;
    if (id < 256) {
        // ---- buildM + center ----
        int px = id & 3, d = (id >> 2) & 31, b = id >> 7;
        int p = px * 256 + threadIdx.x;

        float M[64];
#pragma unroll
        for (int t = 0; t < 64; t++) M[t] = 0.f;
        float c0 = 0.f, c1 = 0.f, c2 = 0.f;

        const float* fbase = fm + (size_t)(b * CIN * PP + p) * 3;
        const float* wbase = W + (size_t)d * CIN * KK * 3;
        const float* wrow = Wc + d * CIN;
        for (int c = 0; c < CIN; c++) {
            const float* f = fbase + c * PP * 3;
            float f0 = f[0], f1 = f[1], f2 = f[2];
            const float* wl = wbase + c * 21;
#pragma unroll
            for (int k = 0; k < KK; k++) {
#pragma unroll
                for (int j = 0; j < 3; j++) {
                    float w = sload(wl, k * 3 + j);
                    M[k * 9 + 0 + j] += w * f0;
                    M[k * 9 + 3 + j] += w * f1;
                    M[k * 9 + 6 + j] += w * f2;
                }
            }
            float wcv = sload(wrow, c);
            c0 += wcv * f0; c1 += wcv * f1; c2 += wcv * f2;
        }
        int gid = ((b * DOUT + d) << 10) + p;
        float4* o = (float4*)(ws + OFF_M + (size_t)gid * 64);
#pragma unroll
        for (int t = 0; t < 15; t++)
            o[t] = make_float4(M[4 * t], M[4 * t + 1], M[4 * t + 2], M[4 * t + 3]);
        o[15] = make_float4(M[60], M[61], M[62], 0.f);
        float* cp = ws + OFF_CEN + (size_t)gid * 3;
        cp[0] = c0; cp[1] = c1; cp[2] = c2;
    } else {
        // ---- pre: ndn + krot ----
        int tid = (id - 256) * 256 + threadIdx.x;
        if (tid < BS * PP * NN) {
            int p = (tid >> 4) & (PP - 1);
            int b = tid >> 14;
            int q = nbr[tid];
            const float* vp = vert + ((b << 10) + p) * 3;
            const float* vq = vert + ((b << 10) + q) * 3;
            float dx = vq[0] - vp[0], dy = vq[1] - vp[1], dz = vq[2] - vp[2];
            float nrm = sqrtf(dx * dx + dy * dy + dz * dz);
            float den = fmaxf(nrm, 1e-12f);
            dx /= den; dy /= den; dz /= den;
            float* o = ws + OFF_NDN + tid * 3;
            o[0] = dx; o[1] = dy; o[2] = dz;
        }
        int t2 = tid - BS * PP * NN;
        if (t2 >= 0 && t2 < DOUT * NR * KK) {
            int k = t2 % KK;
            int r = (t2 / KK) % NR;
            int d = t2 / (KK * NR);
            const float* dk = dirs + (d * KK + k) * 3;
            float x = dk[0], y = dk[1], z = dk[2];
            float nrm = sqrtf(x * x + y * y + z * z);
            float den = fmaxf(nrm, 1e-12f);
            x /= den; y /= den; z /= den;
            const float* R = Rs + r * 9;
            float* o = ws + OFF_KROT + t2 * 3;   // t2 == (d*NR+r)*KK+k
            o[0] = R[0] * x + R[1] * y + R[2] * z;
            o[1] = R[3] * x + R[4] * y + R[5] * z;
            o[2] = R[6] * x + R[7] * y + R[8] * z;
        }
    }
}

// ---------------------------------------------------------------------------
// interleaved-row swizzle (k_score): row p -> float4 slots (p<<2|j)^((p>>1)&7)
// ---------------------------------------------------------------------------
__device__ __forceinline__ int fo_base(int p) {
    return (p << 2) ^ ((p >> 1) & 7);
}

// ---------------------------------------------------------------------------
// k_score: ONE rotation-pair per block (grid 30x32x2 = 1920 blocks).
// FROZEN round-14 version (117 µs): distance-1 prefetch, per-n
// sched_barrier(0) convoy-break, packed fp32 pair math, 64 KiB LDS.
// ---------------------------------------------------------------------------
__global__ __launch_bounds__(1024)
void k_score(const int* __restrict__ nbr,
             const float* __restrict__ Rs,
             const float* __restrict__ Mptr,
             const float* __restrict__ ndn,
             const float* __restrict__ krot,
             float* __restrict__ pval,
             unsigned char* __restrict__ pidx8) {
    __shared__ v4f fo4s[PP * 4];          // 64 KiB exactly
    const int tile = blockIdx.x, d = blockIdx.y, b = blockIdx.z;
    const int bd = b * DOUT + d;
    const int rbase = tile * 2;
    const int tq = threadIdx.x >> 2;      // point-group
    const int ns = threadIdx.x & 3;       // neighbor subset

    // ---- Phase A ----
    {
        const int p = threadIdx.x;
        float Rc0[9], Rc1[9];
#pragma unroll
        for (int j = 0; j < 9; j++) {
            Rc0[j] = sload(Rs, (rbase + 0) * 9 + j);
            Rc1[j] = sload(Rs, (rbase + 1) * 9 + j);
        }
        float fo0[KK], fo1[KK];
#pragma unroll
        for (int k = 0; k < KK; k++) { fo0[k] = 0.f; fo1[k] = 0.f; }

        const float4* m4 = (const float4*)(Mptr + (size_t)((bd << 10) + p) * 64);
#pragma unroll
        for (int t = 0; t < 16; t++) {           // t compile-time
            float4 v = m4[t];
            float e[4] = {v.x, v.y, v.z, v.w};
#pragma unroll
            for (int ee = 0; ee < 4; ee++) {
                const int g = 4 * t + ee;        // compile-time
                if (g < 63) {
                    const int k = g / 9, r9 = g % 9;
                    fo0[k] += Rc0[r9] * e[ee];
                    fo1[k] += Rc1[r9] * e[ee];
                }
            }
            if ((t & 3) == 3)
                __builtin_amdgcn_sched_barrier(0);   // cap in-flight loads
        }
        const int fb = fo_base(p);
        v4f s0; s0.x = fo0[0]; s0.y = fo1[0]; s0.z = fo0[1]; s0.w = fo1[1];
        v4f s1; s1.x = fo0[2]; s1.y = fo1[2]; s1.z = fo0[3]; s1.w = fo1[3];
        v4f s2; s2.x = fo0[4]; s2.y = fo1[4]; s2.z = fo0[5]; s2.w = fo1[5];
        v4f s3; s3.x = fo0[6]; s3.y = fo1[6]; s3.z = 0.f;    s3.w = 0.f;
        fo4s[fb]     = s0;
        fo4s[fb ^ 1] = s1;
        fo4s[fb ^ 2] = s2;
        fo4s[fb ^ 3] = s3;
    }
    __syncthreads();

    // ---- Phase B ----
    v2f vkp[KK][3];   // krot pairs [rr0, rr1] -> SGPR pairs
    {
        const int kb0 = (d * NR + rbase + 0) * 21;
        const int kb1 = (d * NR + rbase + 1) * 21;
#pragma unroll
        for (int k = 0; k < KK; k++)
#pragma unroll
            for (int c = 0; c < 3; c++) {
                v2f t; t.x = sload(krot, kb0 + k * 3 + c);
                       t.y = sload(krot, kb1 + k * 3 + c);
                vkp[k][c] = t;
            }
    }
    const v2f* fo2s = (const v2f*)fo4s;

#pragma unroll
    for (int pp = 0; pp < 4; pp++) {
        const int p2 = (pp << 8) + tq;

        int4 nv = *(const int4*)(nbr + (((size_t)((b << 10) + p2)) << 4) + (ns << 2));
        float u[12];
        {
            const float4* u4 = (const float4*)(ndn + ((size_t)((b << 10) + p2) * 16 + (ns << 2)) * 3);
            float4 a = u4[0], bb = u4[1], cc = u4[2];
            u[0] = a.x;  u[1] = a.y;  u[2] = a.z;  u[3] = a.w;
            u[4] = bb.x; u[5] = bb.y; u[6] = bb.z; u[7] = bb.w;
            u[8] = cc.x; u[9] = cc.y; u[10] = cc.z; u[11] = cc.w;
        }

        float mk0[KK], mk1[KK];
#pragma unroll
        for (int k = 0; k < KK; k++) { mk0[k] = NEG_INF; mk1[k] = NEG_INF; }

        // prefetch n=0 gathers
        int c0 = fo_base(nv.x);
        v4f A = fo4s[c0];
        v4f B = fo4s[c0 ^ 1];
        v4f C = fo4s[c0 ^ 2];
        v2f D = fo2s[(c0 ^ 3) << 1];      // k=6 pair only (b64)

#pragma unroll
        for (int n = 0; n < 4; n++) {     // n compile-time
            v4f An, Bn, Cn; v2f Dn;
            if (n < 3) {
                int qn = (n == 0) ? nv.y : (n == 1) ? nv.z : nv.w;
                int cn = fo_base(qn);
                An = fo4s[cn];
                Bn = fo4s[cn ^ 1];
                Cn = fo4s[cn ^ 2];
                Dn = fo2s[(cn ^ 3) << 1];
            }
            float u0 = u[n * 3], u1 = u[n * 3 + 1], u2 = u[n * 3 + 2];
            v2f u00; u00.x = u0; u00.y = u0;
            v2f u11; u11.x = u1; u11.y = u1;
            v2f u22; u22.x = u2; u22.y = u2;
#pragma unroll
            for (int k = 0; k < KK; k++) {
                v2f g;
                if (k == 0)      g = __builtin_shufflevector(A, A, 0, 1);
                else if (k == 1) g = __builtin_shufflevector(A, A, 2, 3);
                else if (k == 2) g = __builtin_shufflevector(B, B, 0, 1);
                else if (k == 3) g = __builtin_shufflevector(B, B, 2, 3);
                else if (k == 4) g = __builtin_shufflevector(C, C, 0, 1);
                else if (k == 5) g = __builtin_shufflevector(C, C, 2, 3);
                else             g = D;
                v2f t = pk_mul_sv(vkp[k][0], u00);
                t = pk_fma_svv(vkp[k][1], u11, t);
                t = pk_fma_svv(vkp[k][2], u22, t);
                v2f pr = pk_mul_vv(g, t);
                mk0[k] = fmaxf(mk0[k], pr.x);
                mk1[k] = fmaxf(mk1[k], pr.y);
            }
            if (n < 3) { A = An; B = Bn; C = Cn; D = Dn; }
            // break the DS-burst convoy: pin each n's [DS][VALU] region
            __builtin_amdgcn_sched_barrier(0);
        }
        // finish max over 16 neighbors: DPP quad butterfly
#pragma unroll
        for (int k = 0; k < KK; k++) {
            mk0[k] = quad_max(mk0[k]);
            mk1[k] = quad_max(mk1[k]);
        }
        float s0 = ((mk0[0] + mk0[1]) + (mk0[2] + mk0[3])) + ((mk0[4] + mk0[5]) + mk0[6]);
        float s1 = ((mk1[0] + mk1[1]) + (mk1[2] + mk1[3])) + ((mk1[4] + mk1[5]) + mk1[6]);
        float bl = s0; int bil = rbase;
        if (s1 > bl) { bl = s1; bil = rbase + 1; }

        if (ns == 0) {
            int pi = (bd * NT2 + tile) * PP + p2;
            pval[pi] = bl;
            pidx8[pi] = (unsigned char)bil;
        }
    }
}

// ---------------------------------------------------------------------------
// k_reduce: final argmax over 30 pair-partials; fo2[k] = <R_ri, M[p]>
// ---------------------------------------------------------------------------
__global__ __launch_bounds__(256, 2) void k_reduce(const float* __restrict__ Rs,
                                                   float* __restrict__ ws) {
    int gid = blockIdx.x * 256 + threadIdx.x;   // (b*DOUT+d)*PP + p
    int bd = gid >> 10;
    int p = gid & (PP - 1);
    const unsigned char* pidx8 = (const unsigned char*)(ws + OFF_PIDX);
    float best = NEG_INF;
    int bi = 0;
    for (int t = 0; t < NT2; t++) {
        float v = ws[OFF_PVAL + (bd * NT2 + t) * PP + p];
        int idx = pidx8[(bd * NT2 + t) * PP + p];
        if (v > best) { best = v; bi = idx; }
    }
    ((int*)ws)[OFF_RIDX + gid] = bi;

    const float* R = Rs + bi * 9;
    float R0 = R[0], R1 = R[1], R2 = R[2];
    float R3 = R[3], R4 = R[4], R5 = R[5];
    float R6 = R[6], R7 = R[7], R8 = R[8];

    float M[64];
    const float4* m4 = (const float4*)(ws + OFF_M + (size_t)gid * 64);
#pragma unroll
    for (int t = 0; t < 16; t++) {
        float4 v = m4[t];
        M[4 * t] = v.x; M[4 * t + 1] = v.y; M[4 * t + 2] = v.z; M[4 * t + 3] = v.w;
    }
    float* o = ws + OFF_FO2 + (size_t)gid * 8;
#pragma unroll
    for (int k = 0; k < KK; k++) {
        o[k] = R0 * M[k * 9 + 0] + R1 * M[k * 9 + 1] + R2 * M[k * 9 + 2]
             + R3 * M[k * 9 + 3] + R4 * M[k * 9 + 4] + R5 * M[k * 9 + 5]
             + R6 * M[k * 9 + 6] + R7 * M[k * 9 + 7] + R8 * M[k * 9 + 8];
    }
    o[7] = 0.f;
}

// ---------------------------------------------------------------------------
// k_final: theta2 = relu(<krot[ri,k], ndn>), gather neighbor fo2 from LDS,
// kaw = max_n, out = sum_k kaw*krot + cen (precomputed in k_prebuild)
// ---------------------------------------------------------------------------
__global__ __launch_bounds__(256, 2) void k_final(const int* __restrict__ nbr,
                                                  const float* __restrict__ ws,
                                                  float* __restrict__ out) {
    __shared__ float fo2_s[PP * 8];        // 32 KiB
    __shared__ float krot_s[NR * KK * 3];  // 5040 B
    int d = blockIdx.y, b = blockIdx.z;
    int bd = b * DOUT + d;
    for (int i = threadIdx.x; i < PP * 8; i += 256)
        fo2_s[i] = ws[OFF_FO2 + (size_t)bd * PP * 8 + i];
    for (int i = threadIdx.x; i < NR * KK * 3; i += 256)
        krot_s[i] = ws[OFF_KROT + d * NR * KK * 3 + i];
    __syncthreads();

    int p = blockIdx.x * 256 + threadIdx.x;
    int gid = (bd << 10) + p;
    int ri = ((const int*)ws)[OFF_RIDX + gid];

    float v[21];
#pragma unroll
    for (int t = 0; t < 21; t++) v[t] = krot_s[ri * 21 + t];

    float u[48];
    {
        const float4* u4 = (const float4*)(ws + OFF_NDN + (size_t)((b << 10) + p) * 48);
#pragma unroll
        for (int t = 0; t < 12; t++) {
            float4 w = u4[t];
            u[4 * t] = w.x; u[4 * t + 1] = w.y; u[4 * t + 2] = w.z; u[4 * t + 3] = w.w;
        }
    }
    int nidx[16];
    {
        const int4* n4 = (const int4*)(nbr + (size_t)((b << 10) + p) * 16);
#pragma unroll
        for (int t = 0; t < 4; t++) {
            int4 w = n4[t];
            nidx[4 * t] = w.x; nidx[4 * t + 1] = w.y; nidx[4 * t + 2] = w.z; nidx[4 * t + 3] = w.w;
        }
    }

    float kaw[7];
#pragma unroll
    for (int k = 0; k < KK; k++) kaw[k] = NEG_INF;
#pragma unroll
    for (int n = 0; n < NN; n++) {
        int q = nidx[n];
        const float4* fq = (const float4*)&fo2_s[q * 8];
        float4 a = fq[0], c4 = fq[1];
        float g[7] = {a.x, a.y, a.z, a.w, c4.x, c4.y, c4.z};
        float u0 = u[n * 3], u1 = u[n * 3 + 1], u2 = u[n * 3 + 2];
#pragma unroll
        for (int k = 0; k < KK; k++) {
            float th = fmaxf(v[k * 3] * u0 + v[k * 3 + 1] * u1 + v[k * 3 + 2] * u2, 0.f);
            kaw[k] = fmaxf(kaw[k], g[k] * th);
        }
    }
    float o0 = 0.f, o1 = 0.f, o2 = 0.f;
#pragma unroll
    for (int k = 0; k < KK; k++) {
        o0 += kaw[k] * v[k * 3];
        o1 += kaw[k] * v[k * 3 + 1];
        o2 += kaw[k] * v[k * 3 + 2];
    }
    const float* cp = ws + OFF_CEN + (size_t)gid * 3;
    out[(size_t)gid * 3 + 0] = o0 + cp[0];
    out[(size_t)gid * 3 + 1] = o1 + cp[1];
    out[(size_t)gid * 3 + 2] = o2 + cp[2];
}

// ---------------------------------------------------------------------------
extern "C" void kernel_launch(void* const* d_in, const int* in_sizes, int n_in,
                              void* d_out, int out_size, void* d_ws, size_t ws_size,
                              hipStream_t stream) {
    const int*   nbr  = (const int*)d_in[0];
    const float* vert = (const float*)d_in[1];
    const float* fm   = (const float*)d_in[2];
    const float* W    = (const float*)d_in[3];
    const float* Wc   = (const float*)d_in[4];
    const float* dirs = (const float*)d_in[5];
    const float* Rs   = (const float*)d_in[6];
    float* ws  = (float*)d_ws;
    float* out = (float*)d_out;

    k_prebuild<<<437, 256, 0, stream>>>(nbr, vert, dirs, Rs, fm, W, Wc, ws);
    k_score<<<dim3(NT2, DOUT, BS), 1024, 0, stream>>>(
        nbr, Rs, ws + OFF_M, ws + OFF_NDN, ws + OFF_KROT,
        ws + OFF_PVAL, (unsigned char*)(ws + OFF_PIDX));
    k_reduce<<<dim3(BS * DOUT * PP / 256), 256, 0, stream>>>(Rs, ws);
    k_final<<<dim3(PP / 256, DOUT, BS), 256, 0, stream>>>(nbr, ws, out);
}